// Round 7
// baseline (439.487 us; speedup 1.0000x reference)
//
#include <hip/hip_runtime.h>
#include <hip/hip_fp16.h>
#include <math.h>

#define N_NODES 100000
#define N_EDGES 1600000
#define N_ITEMS (N_EDGES + N_NODES)   // edges + self loops
#define F_IN 128
#define F_E 8
#define HC 64      // H*C (layer-1 output width)
#define NHEAD 4
#define NEG 0.2f
#define SCAN_BS 1024
#define SCAN_NB ((N_NODES + SCAN_BS - 1) / SCAN_BS)   // 98
#define MS_BLOCKS 1024
#define NEG_BIG (-3.0e38f)

union H2I { __half2 h; int i; };

// per-block partial sums of edge_attr columns (no atomics); also inits deg=1
__global__ void mean_sum_kernel(const float* __restrict__ ea, float* __restrict__ partials,
                                unsigned* __restrict__ deg) {
    __shared__ float sh[4][8];
    int stride = gridDim.x * blockDim.x;
    for (int i = blockIdx.x * blockDim.x + threadIdx.x; i < N_NODES; i += stride)
        deg[i] = 1u;   // self loop
    float acc[8] = {0.f,0.f,0.f,0.f,0.f,0.f,0.f,0.f};
    for (int r = blockIdx.x * blockDim.x + threadIdx.x; r < N_EDGES; r += stride) {
        const float4* p = (const float4*)(ea + (size_t)r * 8);
        float4 a = p[0], b = p[1];
        acc[0] += a.x; acc[1] += a.y; acc[2] += a.z; acc[3] += a.w;
        acc[4] += b.x; acc[5] += b.y; acc[6] += b.z; acc[7] += b.w;
    }
    int wid  = threadIdx.x >> 6;
    int lane = threadIdx.x & 63;
#pragma unroll
    for (int k = 0; k < 8; k++) {
        float v = acc[k];
        for (int off = 32; off; off >>= 1) v += __shfl_down(v, off);
        if (lane == 0) sh[wid][k] = v;
    }
    __syncthreads();
    if (threadIdx.x < 8) {
        float s = sh[0][threadIdx.x] + sh[1][threadIdx.x] + sh[2][threadIdx.x] + sh[3][threadIdx.x];
        partials[blockIdx.x * 8 + threadIdx.x] = s;
    }
}

// one wave: reduce MS_BLOCKS x 8 partials -> sum8
__global__ void reduce_sum8(const float* __restrict__ partials, float* __restrict__ sum8) {
    int lane = threadIdx.x;       // 64 threads
    int c = lane & 7, g = lane >> 3;
    float s = 0.f;
    for (int b = g; b < MS_BLOCKS; b += 8) s += partials[b * 8 + c];
    s += __shfl_xor(s, 8);
    s += __shfl_xor(s, 16);
    s += __shfl_xor(s, 32);
    if (lane < 8) sum8[lane] = s;
}

__global__ void hist_kernel(const int* __restrict__ dst, unsigned* __restrict__ deg) {
    int e = blockIdx.x * blockDim.x + threadIdx.x;
    if (e < N_EDGES) atomicAdd(&deg[dst[e]], 1u);
}

// inclusive block scan of deg -> local_inc; per-block totals -> bsum
__global__ void scan1(const unsigned* __restrict__ deg, unsigned* __restrict__ local_inc,
                      unsigned* __restrict__ bsum) {
    __shared__ unsigned tmp[SCAN_BS];
    int i = blockIdx.x * SCAN_BS + threadIdx.x;
    unsigned v = (i < N_NODES) ? deg[i] : 0u;
    tmp[threadIdx.x] = v;
    __syncthreads();
    for (int off = 1; off < SCAN_BS; off <<= 1) {
        unsigned add = (threadIdx.x >= (unsigned)off) ? tmp[threadIdx.x - off] : 0u;
        __syncthreads();
        tmp[threadIdx.x] += add;
        __syncthreads();
    }
    if (i < N_NODES) local_inc[i] = tmp[threadIdx.x];
    if (threadIdx.x == SCAN_BS - 1) bsum[blockIdx.x] = tmp[threadIdx.x];
}

// exclusive scan of the 98 block sums (single block of 128)
__global__ void scan2(unsigned* __restrict__ bsum) {
    __shared__ unsigned tmp[128];
    int t = threadIdx.x;
    unsigned v = (t < SCAN_NB) ? bsum[t] : 0u;
    tmp[t] = v;
    __syncthreads();
    for (int off = 1; off < 128; off <<= 1) {
        unsigned add = (t >= off) ? tmp[t - off] : 0u;
        __syncthreads();
        tmp[t] += add;
        __syncthreads();
    }
    if (t < SCAN_NB) bsum[t] = tmp[t] - v;   // exclusive
}

__global__ void scan3(const unsigned* __restrict__ local_inc, const unsigned* __restrict__ deg,
                      const unsigned* __restrict__ bsum,
                      unsigned* __restrict__ row_start, unsigned* __restrict__ next) {
    int i = blockIdx.x * blockDim.x + threadIdx.x;
    if (i >= N_NODES) return;
    unsigned v = local_inc[i] - deg[i] + bsum[i / SCAN_BS];
    row_start[i] = v;
    next[i] = v;
}

// scatter edges (+ self loops) into destination-sorted order; sea stored fp16;
// see2 = ea @ We2 (scalar per item) precomputed for layer 2.
__global__ void scatter_kernel(const int* __restrict__ src, const int* __restrict__ dst,
                               const float* __restrict__ ea, const float* __restrict__ sum8,
                               const float* __restrict__ We2,
                               unsigned* __restrict__ next,
                               int* __restrict__ sorted_src, __half* __restrict__ seah,
                               float* __restrict__ see2) {
    int item = blockIdx.x * blockDim.x + threadIdx.x;
    if (item >= N_ITEMS) return;
    int s, d;
    float4 a, b;
    if (item < N_EDGES) {
        s = src[item]; d = dst[item];
        const float4* p = (const float4*)(ea + (size_t)item * 8);
        a = p[0]; b = p[1];
    } else {
        s = d = item - N_EDGES;
        const float inv = 1.0f / N_EDGES;
        a = make_float4(sum8[0]*inv, sum8[1]*inv, sum8[2]*inv, sum8[3]*inv);
        b = make_float4(sum8[4]*inv, sum8[5]*inv, sum8[6]*inv, sum8[7]*inv);
    }
    float ee2 = a.x*We2[0] + a.y*We2[1] + a.z*We2[2] + a.w*We2[3]
              + b.x*We2[4] + b.y*We2[5] + b.z*We2[6] + b.w*We2[7];
    unsigned pos = atomicAdd(&next[d], 1u);
    sorted_src[pos] = s;
    see2[pos] = ee2;
    H2I p0, p1, p2, p3;
    p0.h = __floats2half2_rn(a.x, a.y);
    p1.h = __floats2half2_rn(a.z, a.w);
    p2.h = __floats2half2_rn(b.x, b.y);
    p3.h = __floats2half2_rn(b.z, b.w);
    *(int4*)(seah + (size_t)pos * 8) = make_int4(p0.i, p1.i, p2.i, p3.i);
}

// xl = x@Wl + bl (stored fp16); xr = x@Wr + br (f32)
__global__ __launch_bounds__(256) void gemm1_kernel(
        const float* __restrict__ x,
        const float* __restrict__ Wl, const float* __restrict__ bl,
        const float* __restrict__ Wr, const float* __restrict__ br,
        __half* __restrict__ xlh, float* __restrict__ xr) {
    __shared__ float xs_t[F_IN][36];      // [k][node], padded -> 18 KiB
    int t = threadIdx.x & 31;             // col-quad: combined cols 4t..4t+3
    int g = threadIdx.x >> 5;             // node-quad: nodes 4g..4g+3 of the tile
    const float* Wsel = (t < 16) ? Wl : Wr;
    const float* bsel = (t < 16) ? bl : br;
    int jc = (t < 16) ? 4 * t : 4 * t - HC;
    float4 bias = *(const float4*)(bsel + jc);

    int n0 = blockIdx.x * 32;             // N_NODES = 32*3125 exactly
    int row = threadIdx.x >> 3;           // 0..31
    int cq  = threadIdx.x & 7;            // col chunk
#pragma unroll
    for (int r = 0; r < 4; r++) {
        int c = cq * 4 + r * 32;
        float4 v = *(const float4*)(x + (size_t)(n0 + row) * F_IN + c);
        xs_t[c + 0][row] = v.x;
        xs_t[c + 1][row] = v.y;
        xs_t[c + 2][row] = v.z;
        xs_t[c + 3][row] = v.w;
    }
    __syncthreads();
    int nb = g * 4;
    float4 a0 = bias, a1 = bias, a2 = bias, a3 = bias;
#pragma unroll 4
    for (int k = 0; k < F_IN; k++) {
        float4 w  = *(const float4*)(Wsel + k * HC + jc);
        float4 xv = *(const float4*)&xs_t[k][nb];
        a0.x += w.x * xv.x; a0.y += w.y * xv.x; a0.z += w.z * xv.x; a0.w += w.w * xv.x;
        a1.x += w.x * xv.y; a1.y += w.y * xv.y; a1.z += w.z * xv.y; a1.w += w.w * xv.y;
        a2.x += w.x * xv.z; a2.y += w.y * xv.z; a2.z += w.z * xv.z; a2.w += w.w * xv.z;
        a3.x += w.x * xv.w; a3.y += w.y * xv.w; a3.z += w.z * xv.w; a3.w += w.w * xv.w;
    }
    if (t < 16) {
        float4 arr[4] = {a0, a1, a2, a3};
#pragma unroll
        for (int r = 0; r < 4; r++) {
            H2I u0, u1;
            u0.h = __floats2half2_rn(arr[r].x, arr[r].y);
            u1.h = __floats2half2_rn(arr[r].z, arr[r].w);
            *(int2*)(xlh + (size_t)(n0 + nb + r) * HC + jc) = make_int2(u0.i, u1.i);
        }
    } else {
        *(float4*)(xr + (size_t)(n0 + nb + 0) * HC + jc) = a0;
        *(float4*)(xr + (size_t)(n0 + nb + 1) * HC + jc) = a1;
        *(float4*)(xr + (size_t)(n0 + nb + 2) * HC + jc) = a2;
        *(float4*)(xr + (size_t)(n0 + nb + 3) * HC + jc) = a3;
    }
}

__device__ __forceinline__ void load_edge(const int* __restrict__ ssrc,
                                          const __half* __restrict__ seah,
                                          const __half* __restrict__ xlh,
                                          unsigned start, unsigned cnt, unsigned idx, int cl,
                                          bool& valid, float4& e0, float4& e1, float4& xv) {
    valid = (idx < cnt);
    unsigned sf = valid ? start + idx : start;
    int s = ssrc[sf];
    int4 r = *(const int4*)(seah + (size_t)sf * 8);
    H2I h0, h1, h2, h3;
    h0.i = r.x; h1.i = r.y; h2.i = r.z; h3.i = r.w;
    float2 f0 = __half22float2(h0.h), f1 = __half22float2(h1.h);
    float2 f2 = __half22float2(h2.h), f3 = __half22float2(h3.h);
    e0 = make_float4(f0.x, f0.y, f1.x, f1.y);
    e1 = make_float4(f2.x, f2.y, f3.x, f3.y);
    int2 xw = *(const int2*)(xlh + (size_t)s * HC + 4 * cl);
    H2I u0, u1; u0.i = xw.x; u1.i = xw.y;
    float2 g0 = __half22float2(u0.h), g1 = __half22float2(u1.h);
    xv = make_float4(g0.x, g0.y, g1.x, g1.y);
}

__device__ __forceinline__ void edge_update(const float4* __restrict__ we,
                                            const float4& attv, const float4& xrv,
                                            bool valid, const float4& ea0, const float4& ea1,
                                            const float4& xlv,
                                            float& m, float& den, float4& acc) {
    float4 v;
    v.x = xlv.x + xrv.x + ea0.x*we[0].x + ea0.y*we[1].x + ea0.z*we[2].x + ea0.w*we[3].x
                        + ea1.x*we[4].x + ea1.y*we[5].x + ea1.z*we[6].x + ea1.w*we[7].x;
    v.y = xlv.y + xrv.y + ea0.x*we[0].y + ea0.y*we[1].y + ea0.z*we[2].y + ea0.w*we[3].y
                        + ea1.x*we[4].y + ea1.y*we[5].y + ea1.z*we[6].y + ea1.w*we[7].y;
    v.z = xlv.z + xrv.z + ea0.x*we[0].z + ea0.y*we[1].z + ea0.z*we[2].z + ea0.w*we[3].z
                        + ea1.x*we[4].z + ea1.y*we[5].z + ea1.z*we[6].z + ea1.w*we[7].z;
    v.w = xlv.w + xrv.w + ea0.x*we[0].w + ea0.y*we[1].w + ea0.z*we[2].w + ea0.w*we[3].w
                        + ea1.x*we[4].w + ea1.y*we[5].w + ea1.z*we[6].w + ea1.w*we[7].w;
    v.x = v.x > 0.f ? v.x : NEG * v.x;
    v.y = v.y > 0.f ? v.y : NEG * v.y;
    v.z = v.z > 0.f ? v.z : NEG * v.z;
    v.w = v.w > 0.f ? v.w : NEG * v.w;
    float prod = v.x*attv.x + v.y*attv.y + v.z*attv.z + v.w*attv.w;
    prod += __shfl_xor(prod, 1);
    prod += __shfl_xor(prod, 2);      // per-head logit in each 4-lane cluster
    float logit = valid ? prod : NEG_BIG;
    float mnew  = fmaxf(m, logit);
    float scale = __expf(m - mnew);
    float p     = valid ? __expf(logit - mnew) : 0.f;
    den   = den   * scale + p;
    acc.x = acc.x * scale + p * xlv.x;
    acc.y = acc.y * scale + p * xlv.y;
    acc.z = acc.z * scale + p * xlv.z;
    acc.w = acc.w * scale + p * xlv.w;
    m = mnew;
}

// fused layer-1: one wave per node, 8 edges per iteration as TWO independent
// online-softmax streams. 16 lanes/edge, 4 ch/lane. fp16 gathers, f32 math.
__global__ void gat1_kernel(const unsigned* __restrict__ row_start, const unsigned* __restrict__ deg,
                            const int* __restrict__ ssrc, const __half* __restrict__ seah,
                            const float* __restrict__ We1, const float* __restrict__ att1,
                            const float* __restrict__ b1,
                            const __half* __restrict__ xlh, const float* __restrict__ xr,
                            const float* __restrict__ Wl2, const float* __restrict__ bl2,
                            const float* __restrict__ Wr2, const float* __restrict__ br2,
                            float* __restrict__ xl2, float* __restrict__ xr2) {
    int node = blockIdx.x * (blockDim.x >> 6) + (threadIdx.x >> 6);
    int lane = threadIdx.x & 63;
    if (node >= N_NODES) return;
    int g  = lane >> 4;          // edge sub-stream 0..3
    int cl = lane & 15;          // channel-slot: channels 4cl..4cl+3
    unsigned start = row_start[node];
    unsigned cnt   = deg[node];

    float4 we[8];
#pragma unroll
    for (int k = 0; k < 8; k++) we[k] = *(const float4*)(We1 + k * HC + 4 * cl);
    float4 attv = *(const float4*)(att1 + 4 * cl);
    float4 xrv  = *(const float4*)(xr + (size_t)node * HC + 4 * cl);

    float mA = NEG_BIG, denA = 0.f, mB = NEG_BIG, denB = 0.f;
    float4 accA = make_float4(0.f,0.f,0.f,0.f), accB = make_float4(0.f,0.f,0.f,0.f);

    // prefetch (depth 1, two streams)
    bool vA_n, vB_n;
    float4 e0A_n, e1A_n, xA_n, e0B_n, e1B_n, xB_n;
    load_edge(ssrc, seah, xlh, start, cnt, g,     cl, vA_n, e0A_n, e1A_n, xA_n);
    load_edge(ssrc, seah, xlh, start, cnt, 4 + g, cl, vB_n, e0B_n, e1B_n, xB_n);

    for (unsigned j = 0; j < cnt; j += 8) {
        bool vA = vA_n, vB = vB_n;
        float4 e0A = e0A_n, e1A = e1A_n, xA = xA_n;
        float4 e0B = e0B_n, e1B = e1B_n, xB = xB_n;
        unsigned jn = j + 8;
        if (jn < cnt) {
            load_edge(ssrc, seah, xlh, start, cnt, jn + g,     cl, vA_n, e0A_n, e1A_n, xA_n);
            load_edge(ssrc, seah, xlh, start, cnt, jn + 4 + g, cl, vB_n, e0B_n, e1B_n, xB_n);
        }
        edge_update(we, attv, xrv, vA, e0A, e1A, xA, mA, denA, accA);
        edge_update(we, attv, xrv, vB, e0B, e1B, xB, mB, denB, accB);
    }
    // merge stream B into A (in-register)
    float m = fmaxf(mA, mB);
    float sA = __expf(mA - m), sB = __expf(mB - m);
    float den = denA * sA + denB * sB;
    float4 acc;
    acc.x = accA.x * sA + accB.x * sB;
    acc.y = accA.y * sA + accB.y * sB;
    acc.z = accA.z * sA + accB.z * sB;
    acc.w = accA.w * sA + accB.w * sB;

    // merge the 4 g-streams (lanes differing in bits 4,5)
    float M = m;
    M = fmaxf(M, __shfl_xor(M, 16));
    M = fmaxf(M, __shfl_xor(M, 32));
    float gs = __expf(m - M);
    den *= gs; acc.x *= gs; acc.y *= gs; acc.z *= gs; acc.w *= gs;
    den   += __shfl_xor(den, 16);   den   += __shfl_xor(den, 32);
    acc.x += __shfl_xor(acc.x, 16); acc.x += __shfl_xor(acc.x, 32);
    acc.y += __shfl_xor(acc.y, 16); acc.y += __shfl_xor(acc.y, 32);
    acc.z += __shfl_xor(acc.z, 16); acc.z += __shfl_xor(acc.z, 32);
    acc.w += __shfl_xor(acc.w, 16); acc.w += __shfl_xor(acc.w, 32);

    float4 b1v  = *(const float4*)(b1 + 4 * cl);
    float4 wl2v = *(const float4*)(Wl2 + 4 * cl);
    float4 wr2v = *(const float4*)(Wr2 + 4 * cl);
    float inv_den = 1.f / den;
    float4 o;
    o.x = acc.x * inv_den + b1v.x;
    o.y = acc.y * inv_den + b1v.y;
    o.z = acc.z * inv_den + b1v.z;
    o.w = acc.w * inv_den + b1v.w;
    o.x = o.x > 0.f ? o.x : expm1f(o.x);
    o.y = o.y > 0.f ? o.y : expm1f(o.y);
    o.z = o.z > 0.f ? o.z : expm1f(o.z);
    o.w = o.w > 0.f ? o.w : expm1f(o.w);
    float sl = o.x*wl2v.x + o.y*wl2v.y + o.z*wl2v.z + o.w*wl2v.w;
    float sr = o.x*wr2v.x + o.y*wr2v.y + o.z*wr2v.z + o.w*wr2v.w;
#pragma unroll
    for (int off = 1; off <= 8; off <<= 1) {
        sl += __shfl_xor(sl, off);
        sr += __shfl_xor(sr, off);
    }
    if (lane == 0) {
        xl2[node] = sl + bl2[0];
        xr2[node] = sr + br2[0];
    }
}

// fused layer-2: one wave per node, lanes parallel over in-edges.
__global__ void gat2_kernel(const unsigned* __restrict__ row_start, const unsigned* __restrict__ deg,
                            const int* __restrict__ sorted_src, const float* __restrict__ see2,
                            const float* __restrict__ att2,
                            const float* __restrict__ xl2, const float* __restrict__ xr2,
                            const float* __restrict__ b2, float* __restrict__ out) {
    int node = blockIdx.x * (blockDim.x >> 6) + (threadIdx.x >> 6);
    int lane = threadIdx.x & 63;
    if (node >= N_NODES) return;
    unsigned start = row_start[node];
    unsigned cnt   = deg[node];
    float xrv = xr2[node];
    float a2  = att2[0];
    float m = -INFINITY, den = 0.f, num = 0.f;
    for (unsigned base = 0; base < cnt; base += 64) {
        unsigned idx = base + lane;
        float logit = -INFINITY, xv = 0.f;
        if (idx < cnt) {
            int s = sorted_src[start + idx];
            float ee = see2[start + idx];
            xv = xl2[s];
            float v = xv + xrv + ee;
            v = v > 0.f ? v : NEG * v;
            logit = a2 * v;
        }
        float mm = logit;
        for (int off = 1; off < 64; off <<= 1) mm = fmaxf(mm, __shfl_xor(mm, off));
        float mnew = fmaxf(m, mm);
        float p  = (idx < cnt) ? __expf(logit - mnew) : 0.f;
        float pn = p * xv;
        for (int off = 1; off < 64; off <<= 1) {
            p  += __shfl_xor(p, off);
            pn += __shfl_xor(pn, off);
        }
        float scale = __expf(m - mnew);
        den = den * scale + p;
        num = num * scale + pn;
        m = mnew;
    }
    if (lane == 0) out[node] = num / den + b2[0];
}

extern "C" void kernel_launch(void* const* d_in, const int* in_sizes, int n_in,
                              void* d_out, int out_size, void* d_ws, size_t ws_size,
                              hipStream_t stream) {
    const float* x    = (const float*)d_in[0];
    const int*   ei   = (const int*)d_in[1];
    const float* ea   = (const float*)d_in[2];
    const float* Wl1  = (const float*)d_in[3];
    const float* bl1  = (const float*)d_in[4];
    const float* Wr1  = (const float*)d_in[5];
    const float* br1  = (const float*)d_in[6];
    const float* We1  = (const float*)d_in[7];
    const float* att1 = (const float*)d_in[8];
    const float* b1   = (const float*)d_in[9];
    const float* Wl2  = (const float*)d_in[10];
    const float* bl2  = (const float*)d_in[11];
    const float* Wr2  = (const float*)d_in[12];
    const float* br2  = (const float*)d_in[13];
    const float* We2  = (const float*)d_in[14];
    const float* att2 = (const float*)d_in[15];
    const float* b2   = (const float*)d_in[16];

    const int* src = ei;              // edge_index row 0
    const int* dst = ei + N_EDGES;    // edge_index row 1

    float* W = (float*)d_ws;
    size_t o = 0;
    float*    sum8      = W + o;               o += 8;
    float*    partials  = W + o;               o += MS_BLOCKS * 8;
    unsigned* deg       = (unsigned*)(W + o);  o += N_NODES;
    unsigned* local_inc = (unsigned*)(W + o);  o += N_NODES;
    unsigned* bsum      = (unsigned*)(W + o);  o += 128;
    unsigned* row_start = (unsigned*)(W + o);  o += N_NODES;
    unsigned* next      = (unsigned*)(W + o);  o += N_NODES;
    int*      ssrc      = (int*)(W + o);       o += N_ITEMS;
    float*    see2      = W + o;               o += N_ITEMS;
    o = (o + 3) & ~(size_t)3;                  // 16B align
    __half*   seah      = (__half*)(W + o);    o += (size_t)N_ITEMS * 4;   // 8 halves/item
    __half*   xl1h      = (__half*)(W + o);    o += (size_t)N_NODES * (HC / 2);
    float*    xr1       = W + o;               o += (size_t)N_NODES * HC;
    float*    xl2       = W + o;               o += N_NODES;
    float*    xr2       = W + o;               o += N_NODES;

    mean_sum_kernel<<<MS_BLOCKS, 256, 0, stream>>>(ea, partials, deg);
    reduce_sum8<<<1, 64, 0, stream>>>(partials, sum8);
    hist_kernel<<<(N_EDGES + 255) / 256, 256, 0, stream>>>(dst, deg);
    scan1<<<SCAN_NB, SCAN_BS, 0, stream>>>(deg, local_inc, bsum);
    scan2<<<1, 128, 0, stream>>>(bsum);
    scan3<<<(N_NODES + 255) / 256, 256, 0, stream>>>(local_inc, deg, bsum, row_start, next);
    scatter_kernel<<<(N_ITEMS + 255) / 256, 256, 0, stream>>>(
        src, dst, ea, sum8, We2, next, ssrc, seah, see2);
    gemm1_kernel<<<N_NODES / 32, 256, 0, stream>>>(x, Wl1, bl1, Wr1, br1, xl1h, xr1);
    gat1_kernel<<<(N_NODES + 3) / 4, 256, 0, stream>>>(
        row_start, deg, ssrc, seah, We1, att1, b1, xl1h, xr1,
        Wl2, bl2, Wr2, br2, xl2, xr2);
    gat2_kernel<<<(N_NODES + 3) / 4, 256, 0, stream>>>(
        row_start, deg, ssrc, see2, att2, xl2, xr2, b2, (float*)d_out);
}

// Round 8
// 439.217 us; speedup vs baseline: 1.0006x; 1.0006x over previous
//
#include <hip/hip_runtime.h>
#include <hip/hip_fp16.h>
#include <math.h>

#define N_NODES 100000
#define N_EDGES 1600000
#define N_ITEMS (N_EDGES + N_NODES)   // edges + self loops
#define F_IN 128
#define F_E 8
#define HC 64      // H*C (layer-1 output width)
#define NHEAD 4
#define NEG 0.2f
#define SCAN_BS 1024
#define SCAN_NB ((N_NODES + SCAN_BS - 1) / SCAN_BS)   // 98
#define MS_BLOCKS 1024
#define NEG_BIG (-3.0e38f)

union H2I { __half2 h; int i; };

// per-block partial sums of edge_attr columns (no atomics); also inits deg=1
__global__ void mean_sum_kernel(const float* __restrict__ ea, float* __restrict__ partials,
                                unsigned* __restrict__ deg) {
    __shared__ float sh[4][8];
    int stride = gridDim.x * blockDim.x;
    for (int i = blockIdx.x * blockDim.x + threadIdx.x; i < N_NODES; i += stride)
        deg[i] = 1u;   // self loop
    float acc[8] = {0.f,0.f,0.f,0.f,0.f,0.f,0.f,0.f};
    for (int r = blockIdx.x * blockDim.x + threadIdx.x; r < N_EDGES; r += stride) {
        const float4* p = (const float4*)(ea + (size_t)r * 8);
        float4 a = p[0], b = p[1];
        acc[0] += a.x; acc[1] += a.y; acc[2] += a.z; acc[3] += a.w;
        acc[4] += b.x; acc[5] += b.y; acc[6] += b.z; acc[7] += b.w;
    }
    int wid  = threadIdx.x >> 6;
    int lane = threadIdx.x & 63;
#pragma unroll
    for (int k = 0; k < 8; k++) {
        float v = acc[k];
        for (int off = 32; off; off >>= 1) v += __shfl_down(v, off);
        if (lane == 0) sh[wid][k] = v;
    }
    __syncthreads();
    if (threadIdx.x < 8) {
        float s = sh[0][threadIdx.x] + sh[1][threadIdx.x] + sh[2][threadIdx.x] + sh[3][threadIdx.x];
        partials[blockIdx.x * 8 + threadIdx.x] = s;
    }
}

// one wave: reduce MS_BLOCKS x 8 partials -> sum8
__global__ void reduce_sum8(const float* __restrict__ partials, float* __restrict__ sum8) {
    int lane = threadIdx.x;       // 64 threads
    int c = lane & 7, g = lane >> 3;
    float s = 0.f;
    for (int b = g; b < MS_BLOCKS; b += 8) s += partials[b * 8 + c];
    s += __shfl_xor(s, 8);
    s += __shfl_xor(s, 16);
    s += __shfl_xor(s, 32);
    if (lane < 8) sum8[lane] = s;
}

__global__ void hist_kernel(const int* __restrict__ dst, unsigned* __restrict__ deg) {
    int e = blockIdx.x * blockDim.x + threadIdx.x;
    if (e < N_EDGES) atomicAdd(&deg[dst[e]], 1u);
}

// inclusive block scan of deg via shfl wave-scans (2 barriers)
__global__ void scan1(const unsigned* __restrict__ deg, unsigned* __restrict__ local_inc,
                      unsigned* __restrict__ bsum) {
    __shared__ unsigned wsum[16];
    int i = blockIdx.x * SCAN_BS + threadIdx.x;
    int lane = threadIdx.x & 63;
    int wid  = threadIdx.x >> 6;          // 0..15
    unsigned v = (i < N_NODES) ? deg[i] : 0u;
    unsigned sc = v;
#pragma unroll
    for (int off = 1; off < 64; off <<= 1) {
        unsigned t = __shfl_up(sc, off);
        if (lane >= off) sc += t;
    }
    if (lane == 63) wsum[wid] = sc;
    __syncthreads();
    if (threadIdx.x < 16) {
        unsigned w = wsum[threadIdx.x];
#pragma unroll
        for (int off = 1; off < 16; off <<= 1) {
            unsigned t = __shfl_up(w, off);
            if ((int)threadIdx.x >= off) w += t;
        }
        wsum[threadIdx.x] = w;
    }
    __syncthreads();
    unsigned base = wid ? wsum[wid - 1] : 0u;
    sc += base;
    if (i < N_NODES) local_inc[i] = sc;
    if (threadIdx.x == SCAN_BS - 1) bsum[blockIdx.x] = sc;
}

// exclusive scan of the 98 block sums (single block of 128)
__global__ void scan2(unsigned* __restrict__ bsum) {
    __shared__ unsigned tmp[128];
    int t = threadIdx.x;
    unsigned v = (t < SCAN_NB) ? bsum[t] : 0u;
    tmp[t] = v;
    __syncthreads();
    for (int off = 1; off < 128; off <<= 1) {
        unsigned add = (t >= off) ? tmp[t - off] : 0u;
        __syncthreads();
        tmp[t] += add;
        __syncthreads();
    }
    if (t < SCAN_NB) bsum[t] = tmp[t] - v;   // exclusive
}

__global__ void scan3(const unsigned* __restrict__ local_inc, const unsigned* __restrict__ deg,
                      const unsigned* __restrict__ bsum,
                      unsigned* __restrict__ row_start, unsigned* __restrict__ next) {
    int i = blockIdx.x * blockDim.x + threadIdx.x;
    if (i >= N_NODES) return;
    unsigned v = local_inc[i] - deg[i] + bsum[i / SCAN_BS];
    row_start[i] = v;
    next[i] = v;
}

// scatter edges (+ self loops) into destination-sorted order; sea stored fp16;
// see2 = ea @ We2 (scalar per item) precomputed for layer 2.
__global__ void scatter_kernel(const int* __restrict__ src, const int* __restrict__ dst,
                               const float* __restrict__ ea, const float* __restrict__ sum8,
                               const float* __restrict__ We2,
                               unsigned* __restrict__ next,
                               int* __restrict__ sorted_src, __half* __restrict__ seah,
                               float* __restrict__ see2) {
    int item = blockIdx.x * blockDim.x + threadIdx.x;
    if (item >= N_ITEMS) return;
    int s, d;
    float4 a, b;
    if (item < N_EDGES) {
        s = src[item]; d = dst[item];
        const float4* p = (const float4*)(ea + (size_t)item * 8);
        a = p[0]; b = p[1];
    } else {
        s = d = item - N_EDGES;
        const float inv = 1.0f / N_EDGES;
        a = make_float4(sum8[0]*inv, sum8[1]*inv, sum8[2]*inv, sum8[3]*inv);
        b = make_float4(sum8[4]*inv, sum8[5]*inv, sum8[6]*inv, sum8[7]*inv);
    }
    float ee2 = a.x*We2[0] + a.y*We2[1] + a.z*We2[2] + a.w*We2[3]
              + b.x*We2[4] + b.y*We2[5] + b.z*We2[6] + b.w*We2[7];
    unsigned pos = atomicAdd(&next[d], 1u);
    sorted_src[pos] = s;
    see2[pos] = ee2;
    H2I p0, p1, p2, p3;
    p0.h = __floats2half2_rn(a.x, a.y);
    p1.h = __floats2half2_rn(a.z, a.w);
    p2.h = __floats2half2_rn(b.x, b.y);
    p3.h = __floats2half2_rn(b.z, b.w);
    *(int4*)(seah + (size_t)pos * 8) = make_int4(p0.i, p1.i, p2.i, p3.i);
}

// xl = x@Wl + bl (stored fp16); xr = x@Wr + br (f32)
__global__ __launch_bounds__(256) void gemm1_kernel(
        const float* __restrict__ x,
        const float* __restrict__ Wl, const float* __restrict__ bl,
        const float* __restrict__ Wr, const float* __restrict__ br,
        __half* __restrict__ xlh, float* __restrict__ xr) {
    __shared__ float xs_t[F_IN][36];      // [k][node], padded -> 18 KiB
    int t = threadIdx.x & 31;             // col-quad: combined cols 4t..4t+3
    int g = threadIdx.x >> 5;             // node-quad: nodes 4g..4g+3 of the tile
    const float* Wsel = (t < 16) ? Wl : Wr;
    const float* bsel = (t < 16) ? bl : br;
    int jc = (t < 16) ? 4 * t : 4 * t - HC;
    float4 bias = *(const float4*)(bsel + jc);

    int n0 = blockIdx.x * 32;             // N_NODES = 32*3125 exactly
    int row = threadIdx.x >> 3;           // 0..31
    int cq  = threadIdx.x & 7;            // col chunk
#pragma unroll
    for (int r = 0; r < 4; r++) {
        int c = cq * 4 + r * 32;
        float4 v = *(const float4*)(x + (size_t)(n0 + row) * F_IN + c);
        xs_t[c + 0][row] = v.x;
        xs_t[c + 1][row] = v.y;
        xs_t[c + 2][row] = v.z;
        xs_t[c + 3][row] = v.w;
    }
    __syncthreads();
    int nb = g * 4;
    float4 a0 = bias, a1 = bias, a2 = bias, a3 = bias;
#pragma unroll 4
    for (int k = 0; k < F_IN; k++) {
        float4 w  = *(const float4*)(Wsel + k * HC + jc);
        float4 xv = *(const float4*)&xs_t[k][nb];
        a0.x += w.x * xv.x; a0.y += w.y * xv.x; a0.z += w.z * xv.x; a0.w += w.w * xv.x;
        a1.x += w.x * xv.y; a1.y += w.y * xv.y; a1.z += w.z * xv.y; a1.w += w.w * xv.y;
        a2.x += w.x * xv.z; a2.y += w.y * xv.z; a2.z += w.z * xv.z; a2.w += w.w * xv.z;
        a3.x += w.x * xv.w; a3.y += w.y * xv.w; a3.z += w.z * xv.w; a3.w += w.w * xv.w;
    }
    if (t < 16) {
        float4 arr[4] = {a0, a1, a2, a3};
#pragma unroll
        for (int r = 0; r < 4; r++) {
            H2I u0, u1;
            u0.h = __floats2half2_rn(arr[r].x, arr[r].y);
            u1.h = __floats2half2_rn(arr[r].z, arr[r].w);
            *(int2*)(xlh + (size_t)(n0 + nb + r) * HC + jc) = make_int2(u0.i, u1.i);
        }
    } else {
        *(float4*)(xr + (size_t)(n0 + nb + 0) * HC + jc) = a0;
        *(float4*)(xr + (size_t)(n0 + nb + 1) * HC + jc) = a1;
        *(float4*)(xr + (size_t)(n0 + nb + 2) * HC + jc) = a2;
        *(float4*)(xr + (size_t)(n0 + nb + 3) * HC + jc) = a3;
    }
}

__device__ __forceinline__ float4 sea_lo(const int4& r) {
    H2I h0, h1; h0.i = r.x; h1.i = r.y;
    float2 f0 = __half22float2(h0.h), f1 = __half22float2(h1.h);
    return make_float4(f0.x, f0.y, f1.x, f1.y);
}
__device__ __forceinline__ float4 sea_hi(const int4& r) {
    H2I h2, h3; h2.i = r.z; h3.i = r.w;
    float2 f2 = __half22float2(h2.h), f3 = __half22float2(h3.h);
    return make_float4(f2.x, f2.y, f3.x, f3.y);
}
__device__ __forceinline__ float4 xl_f(const int2& w) {
    H2I u0, u1; u0.i = w.x; u1.i = w.y;
    float2 g0 = __half22float2(u0.h), g1 = __half22float2(u1.h);
    return make_float4(g0.x, g0.y, g1.x, g1.y);
}

__device__ __forceinline__ void edge_update(const float4* __restrict__ we,
                                            const float4& attv, const float4& xrv,
                                            bool valid, const float4& ea0, const float4& ea1,
                                            const float4& xlv,
                                            float& m, float& den, float4& acc) {
    float4 v;
    v.x = xlv.x + xrv.x + ea0.x*we[0].x + ea0.y*we[1].x + ea0.z*we[2].x + ea0.w*we[3].x
                        + ea1.x*we[4].x + ea1.y*we[5].x + ea1.z*we[6].x + ea1.w*we[7].x;
    v.y = xlv.y + xrv.y + ea0.x*we[0].y + ea0.y*we[1].y + ea0.z*we[2].y + ea0.w*we[3].y
                        + ea1.x*we[4].y + ea1.y*we[5].y + ea1.z*we[6].y + ea1.w*we[7].y;
    v.z = xlv.z + xrv.z + ea0.x*we[0].z + ea0.y*we[1].z + ea0.z*we[2].z + ea0.w*we[3].z
                        + ea1.x*we[4].z + ea1.y*we[5].z + ea1.z*we[6].z + ea1.w*we[7].z;
    v.w = xlv.w + xrv.w + ea0.x*we[0].w + ea0.y*we[1].w + ea0.z*we[2].w + ea0.w*we[3].w
                        + ea1.x*we[4].w + ea1.y*we[5].w + ea1.z*we[6].w + ea1.w*we[7].w;
    v.x = v.x > 0.f ? v.x : NEG * v.x;
    v.y = v.y > 0.f ? v.y : NEG * v.y;
    v.z = v.z > 0.f ? v.z : NEG * v.z;
    v.w = v.w > 0.f ? v.w : NEG * v.w;
    float prod = v.x*attv.x + v.y*attv.y + v.z*attv.z + v.w*attv.w;
    prod += __shfl_xor(prod, 1);
    prod += __shfl_xor(prod, 2);      // per-head logit in each 4-lane cluster
    float logit = valid ? prod : NEG_BIG;
    float mnew  = fmaxf(m, logit);
    float scale = __expf(m - mnew);
    float p     = valid ? __expf(logit - mnew) : 0.f;
    den   = den   * scale + p;
    acc.x = acc.x * scale + p * xlv.x;
    acc.y = acc.y * scale + p * xlv.y;
    acc.z = acc.z * scale + p * xlv.z;
    acc.w = acc.w * scale + p * xlv.w;
    m = mnew;
}

// fused layer-1: one wave per node. Source indices preloaded into registers
// (shfl-sourced, no dependent 2-hop chain). 2 streams x depth-2 packed staging
// ring -> 8 independent VMEM in flight. fp16 gathers, f32 math.
__global__ void gat1_kernel(const unsigned* __restrict__ row_start, const unsigned* __restrict__ deg,
                            const int* __restrict__ ssrc, const __half* __restrict__ seah,
                            const float* __restrict__ We1, const float* __restrict__ att1,
                            const float* __restrict__ b1,
                            const __half* __restrict__ xlh, const float* __restrict__ xr,
                            const float* __restrict__ Wl2, const float* __restrict__ bl2,
                            const float* __restrict__ Wr2, const float* __restrict__ br2,
                            float* __restrict__ xl2, float* __restrict__ xr2) {
    int node = blockIdx.x * (blockDim.x >> 6) + (threadIdx.x >> 6);
    int lane = threadIdx.x & 63;
    if (node >= N_NODES) return;
    int g  = lane >> 4;          // edge sub-stream 0..3
    int cl = lane & 15;          // channel-slot: channels 4cl..4cl+3
    unsigned start = row_start[node];
    unsigned cnt   = deg[node];

    // preload up to 64 source indices (covers ~100% of Poisson-16 nodes)
    int s_reg = ssrc[start + min((unsigned)lane, cnt - 1)];

    float4 we[8];
#pragma unroll
    for (int k = 0; k < 8; k++) we[k] = *(const float4*)(We1 + k * HC + 4 * cl);
    float4 attv = *(const float4*)(att1 + 4 * cl);
    float4 xrv  = *(const float4*)(xr + (size_t)node * HC + 4 * cl);

    float mA = NEG_BIG, denA = 0.f, mB = NEG_BIG, denB = 0.f;
    float4 accA = make_float4(0.f,0.f,0.f,0.f), accB = make_float4(0.f,0.f,0.f,0.f);

    int4 spA0, spA1, spB0, spB1;
    int2 xpA0, xpA1, xpB0, xpB1;

#define ISSUE(S, JJ) do {                                                      \
    unsigned iA_ = min((JJ) + (unsigned)g, cnt - 1);                           \
    unsigned iB_ = min((JJ) + 4u + (unsigned)g, cnt - 1);                      \
    int sA_ = (iA_ < 64u) ? __shfl(s_reg, (int)iA_) : ssrc[start + iA_];       \
    int sB_ = (iB_ < 64u) ? __shfl(s_reg, (int)iB_) : ssrc[start + iB_];       \
    spA##S = *(const int4*)(seah + (size_t)(start + iA_) * 8);                 \
    xpA##S = *(const int2*)(xlh + (size_t)sA_ * HC + 4 * cl);                  \
    spB##S = *(const int4*)(seah + (size_t)(start + iB_) * 8);                 \
    xpB##S = *(const int2*)(xlh + (size_t)sB_ * HC + 4 * cl);                  \
} while (0)

    ISSUE(0, 0u);
    ISSUE(1, 8u);
    for (unsigned j = 0; j < cnt; j += 16) {
        {
            float4 e0A = sea_lo(spA0), e1A = sea_hi(spA0), xA = xl_f(xpA0);
            float4 e0B = sea_lo(spB0), e1B = sea_hi(spB0), xB = xl_f(xpB0);
            if (j + 16 < cnt) ISSUE(0, j + 16);
            edge_update(we, attv, xrv, (j + g) < cnt,      e0A, e1A, xA, mA, denA, accA);
            edge_update(we, attv, xrv, (j + 4 + g) < cnt,  e0B, e1B, xB, mB, denB, accB);
        }
        if (j + 8 < cnt) {
            float4 e0A = sea_lo(spA1), e1A = sea_hi(spA1), xA = xl_f(xpA1);
            float4 e0B = sea_lo(spB1), e1B = sea_hi(spB1), xB = xl_f(xpB1);
            if (j + 24 < cnt) ISSUE(1, j + 24);
            edge_update(we, attv, xrv, (j + 8 + g) < cnt,  e0A, e1A, xA, mA, denA, accA);
            edge_update(we, attv, xrv, (j + 12 + g) < cnt, e0B, e1B, xB, mB, denB, accB);
        }
    }
#undef ISSUE

    // merge stream B into A (in-register)
    float m = fmaxf(mA, mB);
    float sA = __expf(mA - m), sB = __expf(mB - m);
    float den = denA * sA + denB * sB;
    float4 acc;
    acc.x = accA.x * sA + accB.x * sB;
    acc.y = accA.y * sA + accB.y * sB;
    acc.z = accA.z * sA + accB.z * sB;
    acc.w = accA.w * sA + accB.w * sB;

    // merge the 4 g-streams (lanes differing in bits 4,5)
    float M = m;
    M = fmaxf(M, __shfl_xor(M, 16));
    M = fmaxf(M, __shfl_xor(M, 32));
    float gs = __expf(m - M);
    den *= gs; acc.x *= gs; acc.y *= gs; acc.z *= gs; acc.w *= gs;
    den   += __shfl_xor(den, 16);   den   += __shfl_xor(den, 32);
    acc.x += __shfl_xor(acc.x, 16); acc.x += __shfl_xor(acc.x, 32);
    acc.y += __shfl_xor(acc.y, 16); acc.y += __shfl_xor(acc.y, 32);
    acc.z += __shfl_xor(acc.z, 16); acc.z += __shfl_xor(acc.z, 32);
    acc.w += __shfl_xor(acc.w, 16); acc.w += __shfl_xor(acc.w, 32);

    float4 b1v  = *(const float4*)(b1 + 4 * cl);
    float4 wl2v = *(const float4*)(Wl2 + 4 * cl);
    float4 wr2v = *(const float4*)(Wr2 + 4 * cl);
    float inv_den = 1.f / den;
    float4 o;
    o.x = acc.x * inv_den + b1v.x;
    o.y = acc.y * inv_den + b1v.y;
    o.z = acc.z * inv_den + b1v.z;
    o.w = acc.w * inv_den + b1v.w;
    o.x = o.x > 0.f ? o.x : expm1f(o.x);
    o.y = o.y > 0.f ? o.y : expm1f(o.y);
    o.z = o.z > 0.f ? o.z : expm1f(o.z);
    o.w = o.w > 0.f ? o.w : expm1f(o.w);
    float sl = o.x*wl2v.x + o.y*wl2v.y + o.z*wl2v.z + o.w*wl2v.w;
    float sr = o.x*wr2v.x + o.y*wr2v.y + o.z*wr2v.z + o.w*wr2v.w;
#pragma unroll
    for (int off = 1; off <= 8; off <<= 1) {
        sl += __shfl_xor(sl, off);
        sr += __shfl_xor(sr, off);
    }
    if (lane == 0) {
        xl2[node] = sl + bl2[0];
        xr2[node] = sr + br2[0];
    }
}

// fused layer-2: one wave per node, lanes parallel over in-edges.
__global__ void gat2_kernel(const unsigned* __restrict__ row_start, const unsigned* __restrict__ deg,
                            const int* __restrict__ sorted_src, const float* __restrict__ see2,
                            const float* __restrict__ att2,
                            const float* __restrict__ xl2, const float* __restrict__ xr2,
                            const float* __restrict__ b2, float* __restrict__ out) {
    int node = blockIdx.x * (blockDim.x >> 6) + (threadIdx.x >> 6);
    int lane = threadIdx.x & 63;
    if (node >= N_NODES) return;
    unsigned start = row_start[node];
    unsigned cnt   = deg[node];
    float xrv = xr2[node];
    float a2  = att2[0];
    float m = -INFINITY, den = 0.f, num = 0.f;
    for (unsigned base = 0; base < cnt; base += 64) {
        unsigned idx = base + lane;
        float logit = -INFINITY, xv = 0.f;
        if (idx < cnt) {
            int s = sorted_src[start + idx];
            float ee = see2[start + idx];
            xv = xl2[s];
            float v = xv + xrv + ee;
            v = v > 0.f ? v : NEG * v;
            logit = a2 * v;
        }
        float mm = logit;
        for (int off = 1; off < 64; off <<= 1) mm = fmaxf(mm, __shfl_xor(mm, off));
        float mnew = fmaxf(m, mm);
        float p  = (idx < cnt) ? __expf(logit - mnew) : 0.f;
        float pn = p * xv;
        for (int off = 1; off < 64; off <<= 1) {
            p  += __shfl_xor(p, off);
            pn += __shfl_xor(pn, off);
        }
        float scale = __expf(m - mnew);
        den = den * scale + p;
        num = num * scale + pn;
        m = mnew;
    }
    if (lane == 0) out[node] = num / den + b2[0];
}

extern "C" void kernel_launch(void* const* d_in, const int* in_sizes, int n_in,
                              void* d_out, int out_size, void* d_ws, size_t ws_size,
                              hipStream_t stream) {
    const float* x    = (const float*)d_in[0];
    const int*   ei   = (const int*)d_in[1];
    const float* ea   = (const float*)d_in[2];
    const float* Wl1  = (const float*)d_in[3];
    const float* bl1  = (const float*)d_in[4];
    const float* Wr1  = (const float*)d_in[5];
    const float* br1  = (const float*)d_in[6];
    const float* We1  = (const float*)d_in[7];
    const float* att1 = (const float*)d_in[8];
    const float* b1   = (const float*)d_in[9];
    const float* Wl2  = (const float*)d_in[10];
    const float* bl2  = (const float*)d_in[11];
    const float* Wr2  = (const float*)d_in[12];
    const float* br2  = (const float*)d_in[13];
    const float* We2  = (const float*)d_in[14];
    const float* att2 = (const float*)d_in[15];
    const float* b2   = (const float*)d_in[16];

    const int* src = ei;              // edge_index row 0
    const int* dst = ei + N_EDGES;    // edge_index row 1

    float* W = (float*)d_ws;
    size_t o = 0;
    float*    sum8      = W + o;               o += 8;
    float*    partials  = W + o;               o += MS_BLOCKS * 8;
    unsigned* deg       = (unsigned*)(W + o);  o += N_NODES;
    unsigned* local_inc = (unsigned*)(W + o);  o += N_NODES;
    unsigned* bsum      = (unsigned*)(W + o);  o += 128;
    unsigned* row_start = (unsigned*)(W + o);  o += N_NODES;
    unsigned* next      = (unsigned*)(W + o);  o += N_NODES;
    int*      ssrc      = (int*)(W + o);       o += N_ITEMS;
    float*    see2      = W + o;               o += N_ITEMS;
    o = (o + 3) & ~(size_t)3;                  // 16B align
    __half*   seah      = (__half*)(W + o);    o += (size_t)N_ITEMS * 4;   // 8 halves/item
    __half*   xl1h      = (__half*)(W + o);    o += (size_t)N_NODES * (HC / 2);
    float*    xr1       = W + o;               o += (size_t)N_NODES * HC;
    float*    xl2       = W + o;               o += N_NODES;
    float*    xr2       = W + o;               o += N_NODES;

    mean_sum_kernel<<<MS_BLOCKS, 256, 0, stream>>>(ea, partials, deg);
    reduce_sum8<<<1, 64, 0, stream>>>(partials, sum8);
    hist_kernel<<<(N_EDGES + 255) / 256, 256, 0, stream>>>(dst, deg);
    scan1<<<SCAN_NB, SCAN_BS, 0, stream>>>(deg, local_inc, bsum);
    scan2<<<1, 128, 0, stream>>>(bsum);
    scan3<<<(N_NODES + 255) / 256, 256, 0, stream>>>(local_inc, deg, bsum, row_start, next);
    scatter_kernel<<<(N_ITEMS + 255) / 256, 256, 0, stream>>>(
        src, dst, ea, sum8, We2, next, ssrc, seah, see2);
    gemm1_kernel<<<N_NODES / 32, 256, 0, stream>>>(x, Wl1, bl1, Wr1, br1, xl1h, xr1);
    gat1_kernel<<<(N_NODES + 3) / 4, 256, 0, stream>>>(
        row_start, deg, ssrc, seah, We1, att1, b1, xl1h, xr1,
        Wl2, bl2, Wr2, br2, xl2, xr2);
    gat2_kernel<<<(N_NODES + 3) / 4, 256, 0, stream>>>(
        row_start, deg, ssrc, see2, att2, xl2, xr2, b2, (float*)d_out);
}